// Round 3
// baseline (129.467 us; speedup 1.0000x reference)
//
#include <hip/hip_runtime.h>
#include <math.h>

#define D  16     // latent_dim
#define JT 256    // j columns per block == blockDim.x
#define TI 16     // i rows per block

typedef _Float16 half2v __attribute__((ext_vector_type(2)));

__global__ __launch_bounds__(256, 4) void MLPDecoder_68092411511098_kernel(
    const float* __restrict__ z, const float* __restrict__ W1,
    const float* __restrict__ b1, const float* __restrict__ W2,
    const float* __restrict__ b2, float* __restrict__ out, int N)
{
    __shared__ float  sW1[2 * D * D];   // 512 floats: full W1 (32x16 row-major)
    __shared__ float  sZi[TI * D];      // 256 floats: z rows of the i-tile
    __shared__ half2v sGi[TI * 8];      // 128 dwords: gi tile packed (b1 folded)

    const int tid   = threadIdx.x;
    const int jbase = blockIdx.x * JT;
    const int ibase = blockIdx.y * TI;

    // ---- per-thread z row for j (issue global loads early) ----
    float zr[D];
    {
        const float4* zrow = (const float4*)(z + (size_t)(jbase + tid) * D);
        float4 a = zrow[0], b = zrow[1], c = zrow[2], e = zrow[3];
        zr[0]=a.x;  zr[1]=a.y;  zr[2]=a.z;  zr[3]=a.w;
        zr[4]=b.x;  zr[5]=b.y;  zr[6]=b.z;  zr[7]=b.w;
        zr[8]=c.x;  zr[9]=c.y;  zr[10]=c.z; zr[11]=c.w;
        zr[12]=e.x; zr[13]=e.y; zr[14]=e.z; zr[15]=e.w;
    }

    // ---- stage W1 (128 float4) and the z i-tile (64 float4) into LDS ----
    if (tid < 128)      ((float4*)sW1)[tid]       = ((const float4*)W1)[tid];
    else if (tid < 192) ((float4*)sZi)[tid - 128] = ((const float4*)(z + (size_t)ibase * D))[tid - 128];
    __syncthreads();

    // ---- per-thread g_j (fp32, then pack to 8 half2) ----
    float gj[D];
    #pragma unroll
    for (int k = 0; k < D; ++k) gj[k] = 0.0f;
    #pragma unroll
    for (int m = 0; m < D; ++m) {
        const float* wrow = &sW1[(D + m) * D];   // W1_j row -> broadcast b128 reads
        #pragma unroll
        for (int k = 0; k < D; ++k)
            gj[k] = fmaf(zr[m], wrow[k], gj[k]);
    }
    half2v vj[8];
    #pragma unroll
    for (int p = 0; p < 8; ++p) {
        vj[p].x = (_Float16)gj[2 * p];
        vj[p].y = (_Float16)gj[2 * p + 1];
    }

    // ---- cooperative g_i tile: TI*8 = 128 half2 slots, threads 0..127 ----
    if (tid < TI * 8) {
        const int r = tid >> 3, p = tid & 7;
        const int k0 = 2 * p, k1 = k0 + 1;
        float a0 = b1[k0], a1 = b1[k1];          // fold b1 into i-side
        #pragma unroll
        for (int m = 0; m < D; ++m) {
            const float zf = sZi[r * D + m];
            a0 = fmaf(zf, sW1[m * D + k0], a0);  // W1_i = W1[:16]
            a1 = fmaf(zf, sW1[m * D + k1], a1);
        }
        half2v hv; hv.x = (_Float16)a0; hv.y = (_Float16)a1;
        sGi[tid] = hv;
    }

    // ---- uniform small weights ----
    half2v w2v[8];
    #pragma unroll
    for (int p = 0; p < 8; ++p) {
        w2v[p].x = (_Float16)W2[2 * p];          // uniform -> scalar loads
        w2v[p].y = (_Float16)W2[2 * p + 1];
    }
    const float b2s = b2[0];
    const half2v zero = {(_Float16)0.f, (_Float16)0.f};
    __syncthreads();

    // ---- main pairwise loop: one output column per thread, TI rows ----
    float* orow = out + (size_t)ibase * N + jbase + tid;
    #pragma unroll
    for (int ii = 0; ii < TI; ++ii) {
        const half2v* hrow = &sGi[ii * 8];       // broadcast ds_read_b128 x2
        float acc = b2s;
        #pragma unroll
        for (int p = 0; p < 8; ++p) {
            half2v s = hrow[p] + vj[p];                          // v_pk_add_f16
            half2v r = __builtin_elementwise_max(s, zero);       // v_pk_max_f16
#if __has_builtin(__builtin_amdgcn_fdot2)
            acc = __builtin_amdgcn_fdot2(r, w2v[p], acc, false); // v_dot2_f32_f16
#else
            acc += (float)r.x * (float)w2v[p].x + (float)r.y * (float)w2v[p].y;
#endif
        }
        const float e = __expf(-acc);
        orow[(size_t)ii * N] = __builtin_amdgcn_rcpf(1.0f + e);
    }
}

extern "C" void kernel_launch(void* const* d_in, const int* in_sizes, int n_in,
                              void* d_out, int out_size, void* d_ws, size_t ws_size,
                              hipStream_t stream) {
    const float* z  = (const float*)d_in[0];
    const float* W1 = (const float*)d_in[1];
    const float* b1 = (const float*)d_in[2];
    const float* W2 = (const float*)d_in[3];
    const float* b2 = (const float*)d_in[4];
    float* out = (float*)d_out;

    const int N = in_sizes[0] / D;         // 2048
    dim3 grid(N / JT, N / TI);             // (8, 128) = 1024 blocks, 4/CU
    MLPDecoder_68092411511098_kernel<<<grid, dim3(256), 0, stream>>>(
        z, W1, b1, W2, b2, out, N);
}

// Round 4
// 80.184 us; speedup vs baseline: 1.6146x; 1.6146x over previous
//
#include <hip/hip_runtime.h>
#include <math.h>

#define D  16     // latent_dim
#define JT 256    // j columns per block == blockDim.x
#define TI 16     // i rows per block
#define ZPAD 17   // padded row stride for sZj (conflict-free: 17 coprime 32)

typedef _Float16 half2v __attribute__((ext_vector_type(2)));

__global__ __launch_bounds__(256) void MLPDecoder_68092411511098_kernel(
    const float* __restrict__ z, const float* __restrict__ W1,
    const float* __restrict__ b1, const float* __restrict__ W2,
    const float* __restrict__ b2, float* __restrict__ out, int N)
{
    __shared__ float  sZj[JT * ZPAD];   // 17408 B: z rows of the j-tile (padded)
    __shared__ float  sW1[2 * D * D];   //  2048 B: full W1 (32x16 row-major)
    __shared__ float  sZi[TI * D];      //  1024 B: z rows of the i-tile
    __shared__ half2v sGi[TI * 8];      //   512 B: gi tile packed (b1 folded)

    const int tid   = threadIdx.x;
    const int jbase = blockIdx.x * JT;
    const int ibase = blockIdx.y * TI;

    // ---- stage: each thread parks its j-row in LDS (registers stay transient) ----
    {
        const float4* zrow = (const float4*)(z + (size_t)(jbase + tid) * D);
        float* dst = &sZj[tid * ZPAD];
        #pragma unroll
        for (int q = 0; q < 4; ++q) {
            float4 v = zrow[q];
            dst[4*q+0] = v.x; dst[4*q+1] = v.y; dst[4*q+2] = v.z; dst[4*q+3] = v.w;
        }
    }
    if (tid < 128)      ((float4*)sW1)[tid]       = ((const float4*)W1)[tid];
    else if (tid < 192) ((float4*)sZi)[tid - 128] = ((const float4*)(z + (size_t)ibase * D))[tid - 128];
    __syncthreads();

    // ---- per-thread g_j: operands stream from LDS, only gj[16] accumulates ----
    float gj[D];
    #pragma unroll
    for (int k = 0; k < D; ++k) gj[k] = 0.0f;
    #pragma unroll
    for (int m = 0; m < D; ++m) {
        const float zf   = sZj[tid * ZPAD + m];  // conflict-free (stride 17)
        const float* wrow = &sW1[(D + m) * D];   // same addr all lanes -> broadcast
        #pragma unroll
        for (int k = 0; k < D; ++k)
            gj[k] = fmaf(zf, wrow[k], gj[k]);
    }
    half2v vj[8];
    #pragma unroll
    for (int p = 0; p < 8; ++p) {
        vj[p].x = (_Float16)gj[2 * p];
        vj[p].y = (_Float16)gj[2 * p + 1];
    }

    // ---- cooperative g_i tile: TI*8 = 128 half2 slots, threads 0..127 ----
    if (tid < TI * 8) {
        const int r = tid >> 3, p = tid & 7;
        const int k0 = 2 * p, k1 = k0 + 1;
        float a0 = b1[k0], a1 = b1[k1];          // fold b1 into i-side
        #pragma unroll
        for (int m = 0; m < D; ++m) {
            const float zf = sZi[r * D + m];
            a0 = fmaf(zf, sW1[m * D + k0], a0);  // W1_i = W1[:16]
            a1 = fmaf(zf, sW1[m * D + k1], a1);
        }
        half2v hv; hv.x = (_Float16)a0; hv.y = (_Float16)a1;
        sGi[tid] = hv;
    }

    // ---- uniform small weights (scalar loads) ----
    half2v w2v[8];
    #pragma unroll
    for (int p = 0; p < 8; ++p) {
        w2v[p].x = (_Float16)W2[2 * p];
        w2v[p].y = (_Float16)W2[2 * p + 1];
    }
    const float b2s = b2[0];
    const half2v zero = {(_Float16)0.f, (_Float16)0.f};
    __syncthreads();

    // ---- main pairwise loop: one output column per thread, TI rows ----
    float* orow = out + (size_t)ibase * N + jbase + tid;
    #pragma unroll 4
    for (int ii = 0; ii < TI; ++ii) {
        const half2v* hrow = &sGi[ii * 8];       // broadcast ds_read_b128 x2
        float acc = b2s;
        #pragma unroll
        for (int p = 0; p < 8; ++p) {
            half2v s = hrow[p] + vj[p];                          // v_pk_add_f16
            half2v r = __builtin_elementwise_max(s, zero);       // v_pk_max_f16
#if __has_builtin(__builtin_amdgcn_fdot2)
            acc = __builtin_amdgcn_fdot2(r, w2v[p], acc, false); // v_dot2_f32_f16
#else
            acc += (float)r.x * (float)w2v[p].x + (float)r.y * (float)w2v[p].y;
#endif
        }
        const float e = __expf(-acc);
        orow[(size_t)ii * N] = __builtin_amdgcn_rcpf(1.0f + e);
    }
}

extern "C" void kernel_launch(void* const* d_in, const int* in_sizes, int n_in,
                              void* d_out, int out_size, void* d_ws, size_t ws_size,
                              hipStream_t stream) {
    const float* z  = (const float*)d_in[0];
    const float* W1 = (const float*)d_in[1];
    const float* b1 = (const float*)d_in[2];
    const float* W2 = (const float*)d_in[3];
    const float* b2 = (const float*)d_in[4];
    float* out = (float*)d_out;

    const int N = in_sizes[0] / D;         // 2048
    dim3 grid(N / JT, N / TI);             // (8, 128) = 1024 blocks
    MLPDecoder_68092411511098_kernel<<<grid, dim3(256), 0, stream>>>(
        z, W1, b1, W2, b2, out, N);
}

// Round 5
// 73.912 us; speedup vs baseline: 1.7516x; 1.0849x over previous
//
#include <hip/hip_runtime.h>
#include <math.h>

#define D  16     // latent_dim
#define JT 256    // j columns per block == blockDim.x
#define TI 32     // i rows per block

typedef _Float16 half2v __attribute__((ext_vector_type(2)));

__global__ __launch_bounds__(256) void MLPDecoder_68092411511098_kernel(
    const float* __restrict__ z, const float* __restrict__ W1,
    const float* __restrict__ b1, const float* __restrict__ W2,
    const float* __restrict__ b2, float* __restrict__ out, int N)
{
    __shared__ float  sW1[2 * D * D];   // 512 floats: full W1 (32x16 row-major)
    __shared__ float  sZi[TI * D];      // 512 floats: z rows of the i-tile
    __shared__ half2v sGi[TI * 8];      // 256 half2: gi tile packed (b1 folded)

    const int tid   = threadIdx.x;
    const int jbase = blockIdx.x * JT;
    const int ibase = blockIdx.y * TI;

    // ---- per-thread z j-row into registers (transient; no VGPR cap -> no spill) ----
    float zr[D];
    {
        const float4* zrow = (const float4*)(z + (size_t)(jbase + tid) * D);
        float4 a = zrow[0], b = zrow[1], c = zrow[2], e = zrow[3];
        zr[0]=a.x;  zr[1]=a.y;  zr[2]=a.z;  zr[3]=a.w;
        zr[4]=b.x;  zr[5]=b.y;  zr[6]=b.z;  zr[7]=b.w;
        zr[8]=c.x;  zr[9]=c.y;  zr[10]=c.z; zr[11]=c.w;
        zr[12]=e.x; zr[13]=e.y; zr[14]=e.z; zr[15]=e.w;
    }

    // ---- stage W1 (128 float4) + z i-tile (128 float4) ----
    if (tid < 128) ((float4*)sW1)[tid]       = ((const float4*)W1)[tid];
    else           ((float4*)sZi)[tid - 128] = ((const float4*)(z + (size_t)ibase * D))[tid - 128];
    __syncthreads();

    // ---- per-thread g_j (fp32 accumulate, then pack to 8 half2) ----
    float gj[D];
    #pragma unroll
    for (int k = 0; k < D; ++k) gj[k] = 0.0f;
    #pragma unroll
    for (int m = 0; m < D; ++m) {
        const float* wrow = &sW1[(D + m) * D];   // same addr all lanes -> broadcast
        #pragma unroll
        for (int k = 0; k < D; ++k)
            gj[k] = fmaf(zr[m], wrow[k], gj[k]);
    }
    half2v vj[8];
    #pragma unroll
    for (int p = 0; p < 8; ++p) {
        vj[p].x = (_Float16)gj[2 * p];
        vj[p].y = (_Float16)gj[2 * p + 1];
    }

    // ---- cooperative g_i tile: TI*8 = 256 half2 slots == all threads ----
    {
        const int r = tid >> 3, p = tid & 7;
        const int k0 = 2 * p, k1 = k0 + 1;
        float a0 = b1[k0], a1 = b1[k1];          // fold b1 into i-side
        #pragma unroll
        for (int m = 0; m < D; ++m) {
            const float zf = sZi[r * D + m];
            a0 = fmaf(zf, sW1[m * D + k0], a0);  // W1_i = W1[:16]
            a1 = fmaf(zf, sW1[m * D + k1], a1);
        }
        half2v hv; hv.x = (_Float16)a0; hv.y = (_Float16)a1;
        sGi[tid] = hv;
    }

    // ---- uniform small weights (scalar loads) ----
    half2v w2v[8];
    #pragma unroll
    for (int p = 0; p < 8; ++p) {
        w2v[p].x = (_Float16)W2[2 * p];
        w2v[p].y = (_Float16)W2[2 * p + 1];
    }
    const float b2s = b2[0];
    const half2v zero = {(_Float16)0.f, (_Float16)0.f};
    __syncthreads();

    // ---- main pairwise loop: one output column per thread, TI rows ----
    float* orow = out + (size_t)ibase * N + jbase + tid;
    #pragma unroll 8
    for (int ii = 0; ii < TI; ++ii) {
        const half2v* hrow = &sGi[ii * 8];       // broadcast ds_read_b128 x2
        float acc = b2s;
        #pragma unroll
        for (int p = 0; p < 8; ++p) {
            half2v s = hrow[p] + vj[p];                          // v_pk_add_f16
            half2v r = __builtin_elementwise_max(s, zero);       // v_pk_max_f16
#if __has_builtin(__builtin_amdgcn_fdot2)
            acc = __builtin_amdgcn_fdot2(r, w2v[p], acc, false); // v_dot2_f32_f16
#else
            acc += (float)r.x * (float)w2v[p].x + (float)r.y * (float)w2v[p].y;
#endif
        }
        const float e = __expf(-acc);
        orow[(size_t)ii * N] = __builtin_amdgcn_rcpf(1.0f + e);
    }
}

extern "C" void kernel_launch(void* const* d_in, const int* in_sizes, int n_in,
                              void* d_out, int out_size, void* d_ws, size_t ws_size,
                              hipStream_t stream) {
    const float* z  = (const float*)d_in[0];
    const float* W1 = (const float*)d_in[1];
    const float* b1 = (const float*)d_in[2];
    const float* W2 = (const float*)d_in[3];
    const float* b2 = (const float*)d_in[4];
    float* out = (float*)d_out;

    const int N = in_sizes[0] / D;         // 2048
    dim3 grid(N / JT, N / TI);             // (8, 64) = 512 blocks
    MLPDecoder_68092411511098_kernel<<<grid, dim3(256), 0, stream>>>(
        z, W1, b1, W2, b2, out, N);
}